// Round 3
// baseline (455.501 us; speedup 1.0000x reference)
//
#include <hip/hip_runtime.h>

// AggregateSet fused kernel, MI355X (gfx950).
// Shapes: B=1024, M_ELEM=128, D_IN=64, D_HID=256, H=8, D_K=D_V=64.
// R2: latency-bound fix. Each wave owns 32 e-rows; GEMM2 A-frags live in
// 64 VGPRs (loaded once via per-wave 8KB LDS transpose buffer, K in 2
// halves). Frag K-layout chosen CONTIGUOUS (reg j <-> k=32ks+8lg+j, same
// for A and B -> permutation cancels in MFMA), so every frag load is one
// 16B dwordx4. Softmax/pool are cross-wave (2 barriers/head + 1 final).
// LDS 41KB -> 3 blocks/CU (12 waves/CU), launch_bounds(256,3).

typedef __attribute__((ext_vector_type(8))) short bf16x8;
typedef __attribute__((ext_vector_type(4))) float f32x4;

#define XROW 8320
#define MASK_OFF 8192

static __device__ __forceinline__ short f2bf(float f) {
  union { float f; unsigned u; } v; v.f = f;
  unsigned r = v.u + 0x7FFFu + ((v.u >> 16) & 1u);  // RNE
  return (short)(r >> 16);
}
static __device__ __forceinline__ f32x4 splat4(float v) {
  f32x4 r = {v, v, v, v};
  return r;
}

// ---------------------------------------------------------------------------
// Weight prep: fp32 row-major W[k][n] -> bf16 transposed Wt[n][k] in d_ws.
//   Wt_sub [256][64] @0 ; Wt_q [512][256] @16384 ; Wt_k @147456 ; Wt_v @278528
__global__ __launch_bounds__(256) void prep_weights(
    const float* __restrict__ Ws, const float* __restrict__ Wq,
    const float* __restrict__ Wk, const float* __restrict__ Wv,
    short* __restrict__ wt)
{
  int tid = blockIdx.x * 256 + threadIdx.x;   // grid is exactly 1600*256
  if (tid < 16384) {
    int n = tid >> 6, k = tid & 63;
    wt[tid] = f2bf(Ws[k * 256 + n]);
  } else {
    int idx = tid - 16384;
    int m = idx >> 17;            // 0:q 1:k 2:v
    int r = idx & 131071;
    int n = r >> 8, k = r & 255;
    const float* W = (m == 0) ? Wq : (m == 1) ? Wk : Wv;
    wt[tid] = f2bf(W[k * 512 + n]);
  }
}

__global__ __launch_bounds__(256, 3) void fused_kernel(
    const float* __restrict__ x,
    const float* __restrict__ bsub, const float* __restrict__ bq,
    const float* __restrict__ bk,   const float* __restrict__ bv,
    const short* __restrict__ wt,   float* __restrict__ out)
{
  // per-wave transpose buffer: 32 rows x 128 cols bf16, 16B-granule XOR swz
  __shared__ short activ[4 * 32 * 128];   // 32 KB
  __shared__ float plbuf[8 * 4 * 64];     // 8 KB  [h][w][d]
  __shared__ float redb[8];               // [0..3]=max, [4..7]=esum

  const int b   = blockIdx.x;
  const int tid = threadIdx.x;
  const int w   = tid >> 6;
  const int l   = tid & 63;
  const int l15 = l & 15;
  const int lg  = l >> 4;

  const float* xb  = x + (size_t)b * XROW;
  const short* wts = wt;
  const short* wtq = wt + 16384;
  const short* wtk = wtq + 131072;
  const short* wtv = wtk + 131072;
  short* aw = activ + w * 4096;     // this wave's 8 KB region

  // mask registers for this wave's 32 e-rows: e = 32w + 16mt + 4lg + r
  float mreg[8];
  #pragma unroll
  for (int mt = 0; mt < 2; ++mt)
    #pragma unroll
    for (int r = 0; r < 4; ++r)
      mreg[mt * 4 + r] = xb[MASK_OFF + 32 * w + 16 * mt + 4 * lg + r];

  // xe A-frags (K=64): reg j <-> k = 32ks1 + 8lg + j
  bf16x8 a1[2][2];
  #pragma unroll
  for (int mt = 0; mt < 2; ++mt)
    #pragma unroll
    for (int ks1 = 0; ks1 < 2; ++ks1) {
      int e = 32 * w + 16 * mt + l15;
      const float* p = xb + e * 64 + 32 * ks1 + 8 * lg;
      float4 f0 = *(const float4*)p;
      float4 f1 = *(const float4*)(p + 4);
      bf16x8 t;
      t[0] = f2bf(f0.x); t[1] = f2bf(f0.y); t[2] = f2bf(f0.z); t[3] = f2bf(f0.w);
      t[4] = f2bf(f1.x); t[5] = f2bf(f1.y); t[6] = f2bf(f1.z); t[7] = f2bf(f1.w);
      a1[mt][ks1] = t;
    }

  // ---- GEMM1 (activ = xe@Wsub + b) in 2 K-halves; A-frags -> registers ----
  bf16x8 af[16];   // [ks*2+mt], ks = global 0..7 over D_HID=256
  #pragma unroll
  for (int kh = 0; kh < 2; ++kh) {
    #pragma unroll 1
    for (int nt2 = 0; nt2 < 8; ++nt2) {
      int n = 128 * kh + 16 * nt2 + l15;       // activ col (global)
      float bias = bsub[n];
      f32x4 acc[2];
      acc[0] = splat4(bias); acc[1] = splat4(bias);
      #pragma unroll
      for (int ks1 = 0; ks1 < 2; ++ks1) {
        bf16x8 bfw = *(const bf16x8*)(wts + n * 64 + 32 * ks1 + 8 * lg);
        #pragma unroll
        for (int mt = 0; mt < 2; ++mt)
          acc[mt] = __builtin_amdgcn_mfma_f32_16x16x32_bf16(
              a1[mt][ks1], bfw, acc[mt], 0, 0, 0);
      }
      // C write: row e' = 16mt+4lg+r, local col k = 16nt2+l15, swizzled
      #pragma unroll
      for (int mt = 0; mt < 2; ++mt) {
        #pragma unroll
        for (int r = 0; r < 4; ++r) {
          int ep = 16 * mt + 4 * lg + r;
          int k  = 16 * nt2 + l15;
          int g  = ((k >> 3) ^ (ep & 15)) << 3;
          aw[ep * 128 + (g | (k & 7))] = f2bf(acc[mt][r]);
        }
      }
    }
    // read this half's A-frags into registers (same-wave lgkm ordering)
    #pragma unroll
    for (int ks2 = 0; ks2 < 4; ++ks2)
      #pragma unroll
      for (int mt = 0; mt < 2; ++mt) {
        int ep = 16 * mt + l15;
        int g  = ((4 * ks2 + lg) ^ (ep & 15)) << 3;
        af[(4 * kh + ks2) * 2 + mt] = *(const bf16x8*)(aw + ep * 128 + g);
      }
  }

  // ---------------- per-head: qk -> softmax (cross-wave) -> v -------------
  #pragma unroll 1
  for (int h = 0; h < 8; ++h) {
    float pl[8];
    #pragma unroll
    for (int i = 0; i < 8; ++i) pl[i] = 0.f;

    #pragma unroll 1
    for (int nt = 0; nt < 4; ++nt) {
      int n = h * 64 + 16 * nt + l15;
      f32x4 aq[2], ak[2];
      float biq = bq[n], bik = bk[n];
      aq[0] = splat4(biq); aq[1] = splat4(biq);
      ak[0] = splat4(bik); ak[1] = splat4(bik);
      const short* pq = wtq + n * 256 + 8 * lg;
      const short* pk = wtk + n * 256 + 8 * lg;
      #pragma unroll
      for (int ks = 0; ks < 8; ++ks) {
        bf16x8 bqf = *(const bf16x8*)(pq + 32 * ks);
        bf16x8 bkf = *(const bf16x8*)(pk + 32 * ks);
        #pragma unroll
        for (int mt = 0; mt < 2; ++mt) {
          aq[mt] = __builtin_amdgcn_mfma_f32_16x16x32_bf16(
              af[ks * 2 + mt], bqf, aq[mt], 0, 0, 0);
          ak[mt] = __builtin_amdgcn_mfma_f32_16x16x32_bf16(
              af[ks * 2 + mt], bkf, ak[mt], 0, 0, 0);
        }
      }
      #pragma unroll
      for (int mt = 0; mt < 2; ++mt)
        #pragma unroll
        for (int r = 0; r < 4; ++r)
          pl[mt * 4 + r] += aq[mt][r] * ak[mt][r];
    }
    // reduce partial dots over the 16 d-lanes; scale 1/sqrt(64)
    #pragma unroll
    for (int i = 0; i < 8; ++i) {
      float s = pl[i];
      s += __shfl_xor(s, 1);
      s += __shfl_xor(s, 2);
      s += __shfl_xor(s, 4);
      s += __shfl_xor(s, 8);
      pl[i] = s * 0.125f;
    }

    // local masked max (relu floor 0), then cross-wave
    float zl = 0.f;
    #pragma unroll
    for (int i = 0; i < 8; ++i)
      zl = fmaxf(zl, (mreg[i] > 0.f) ? pl[i] : 0.f);
    zl = fmaxf(zl, __shfl_xor(zl, 16));
    zl = fmaxf(zl, __shfl_xor(zl, 32));
    if (l == 0) redb[w] = zl;
    __syncthreads();
    float zg = fmaxf(fmaxf(redb[0], redb[1]), fmaxf(redb[2], redb[3]));

    float el = 0.f;
    #pragma unroll
    for (int i = 0; i < 8; ++i) {
      float ev = (mreg[i] > 0.f) ? __expf(pl[i] - zg) : 0.f;
      pl[i] = ev;
      el += ev;
    }
    el += __shfl_xor(el, 16);
    el += __shfl_xor(el, 32);
    if (l == 0) redb[4 + w] = el;
    __syncthreads();
    float inv = 1.f / (redb[4] + redb[5] + redb[6] + redb[7] + 1.f);
    #pragma unroll
    for (int i = 0; i < 8; ++i) pl[i] *= inv;

    // v projection + attn-weighted fold (partial over this wave's 32 e)
    #pragma unroll 1
    for (int nt = 0; nt < 4; ++nt) {
      int n = h * 64 + 16 * nt + l15;
      f32x4 av[2];
      float biv = bv[n];
      av[0] = splat4(biv); av[1] = splat4(biv);
      const short* pv = wtv + n * 256 + 8 * lg;
      #pragma unroll
      for (int ks = 0; ks < 8; ++ks) {
        bf16x8 bvf = *(const bf16x8*)(pv + 32 * ks);
        #pragma unroll
        for (int mt = 0; mt < 2; ++mt)
          av[mt] = __builtin_amdgcn_mfma_f32_16x16x32_bf16(
              af[ks * 2 + mt], bvf, av[mt], 0, 0, 0);
      }
      float t = 0.f;
      #pragma unroll
      for (int mt = 0; mt < 2; ++mt)
        #pragma unroll
        for (int r = 0; r < 4; ++r)
          t += pl[mt * 4 + r] * av[mt][r];
      t += __shfl_xor(t, 16);
      t += __shfl_xor(t, 32);
      if (lg == 0) plbuf[h * 256 + w * 64 + 16 * nt + l15] = t;
    }
  }
  __syncthreads();

  // final: wave w writes heads w and w+4 (sum 4 wave-partials)
  #pragma unroll
  for (int hi = 0; hi < 2; ++hi) {
    int h = w + 4 * hi;
    float s = plbuf[h * 256 + l] + plbuf[h * 256 + 64 + l] +
              plbuf[h * 256 + 128 + l] + plbuf[h * 256 + 192 + l];
    out[b * 513 + h * 64 + l] = s;
  }
  // elem_frac (exact: mask is 0/1)
  if (tid < 64) {
    float s = xb[MASK_OFF + tid] + xb[MASK_OFF + tid + 64];
    #pragma unroll
    for (int off = 32; off > 0; off >>= 1) s += __shfl_xor(s, off);
    if (tid == 0) out[b * 513 + 512] = s * (1.f / 128.f);
  }
}

extern "C" void kernel_launch(void* const* d_in, const int* in_sizes, int n_in,
                              void* d_out, int out_size, void* d_ws, size_t ws_size,
                              hipStream_t stream) {
  (void)in_sizes; (void)n_in; (void)out_size; (void)ws_size;
  const float* x    = (const float*)d_in[0];
  const float* Wsub = (const float*)d_in[1];
  const float* bsub = (const float*)d_in[2];
  const float* Wq   = (const float*)d_in[3];
  const float* bq   = (const float*)d_in[4];
  const float* Wk   = (const float*)d_in[5];
  const float* bk   = (const float*)d_in[6];
  const float* Wv   = (const float*)d_in[7];
  const float* bv   = (const float*)d_in[8];
  float* out = (float*)d_out;
  short* wt  = (short*)d_ws;   // 800 KB used

  prep_weights<<<1600, 256, 0, stream>>>(Wsub, Wq, Wk, Wv, wt);
  fused_kernel<<<1024, 256, 0, stream>>>(x, bsub, bq, bk, bv, wt, out);
}